// Round 1
// baseline (9.416 us; speedup 1.0000x reference)
//
#include <hip/hip_runtime.h>

#define NH 32
#define DIM 128
#define NR 16
#define MN 17   // only top-left 17x17 block is non-identity

__global__ __launch_bounds__(256) void givens_rotation_kernel(
    const float* __restrict__ thetas,  // [NH][NR] f32
    float* __restrict__ out)           // [NH][DIM][DIM] f32
{
    // grid = NH * 8 blocks; each block writes 16 rows of one head.
    const int head  = blockIdx.x >> 3;
    const int chunk = blockIdx.x & 7;
    const int tid   = threadIdx.x;

    __shared__ float M[MN][MN];
    __shared__ float cs[NR], sn[NR];

    if (tid < NR) {
        float th = thetas[head * NR + tid];
        cs[tid] = cosf(th);
        sn[tid] = sinf(th);
    }
    __syncthreads();

    // Threads 0..16: each owns one column of the 17x17 block and replays
    // the scan. All rotations are (0, r+1): row0 accumulates; row j=r+1
    // is finalized at step r and never touched again.
    if (tid < MN) {
        const int col = tid;
        float row0 = (col == 0) ? 1.0f : 0.0f;
        #pragma unroll
        for (int r = 0; r < NR; ++r) {
            const int j = r + 1;
            const float qj = (col == j) ? 1.0f : 0.0f;
            const float c = cs[r], s = sn[r];
            M[j][col] = -s * row0 + c * qj;
            row0 = c * row0 + s * qj;
        }
        M[0][col] = row0;
    }
    __syncthreads();

    // Emit rows [chunk*16, chunk*16+16) of this head's 128x128 matrix.
    // 16 rows * 128 cols = 512 float4; 256 threads -> 2 float4 each.
    float* outh = out + (size_t)head * DIM * DIM;
    const int row_base = chunk * 16;
    #pragma unroll
    for (int it = 0; it < 2; ++it) {
        const int idx = it * 256 + tid;        // float4 index within slab
        const int row = row_base + (idx >> 5); // 32 float4 per row
        const int c4  = (idx & 31) * 4;
        float4 v;
        float vals[4];
        #pragma unroll
        for (int k = 0; k < 4; ++k) {
            const int col = c4 + k;
            float x;
            if (row < MN && col < MN) x = M[row][col];
            else                      x = (row == col) ? 1.0f : 0.0f;
            vals[k] = x;
        }
        v.x = vals[0]; v.y = vals[1]; v.z = vals[2]; v.w = vals[3];
        *reinterpret_cast<float4*>(outh + row * DIM + c4) = v;
    }
}

extern "C" void kernel_launch(void* const* d_in, const int* in_sizes, int n_in,
                              void* d_out, int out_size, void* d_ws, size_t ws_size,
                              hipStream_t stream) {
    const float* thetas = (const float*)d_in[0];
    float* out = (float*)d_out;
    dim3 grid(NH * 8);
    dim3 block(256);
    givens_rotation_kernel<<<grid, block, 0, stream>>>(thetas, out);
}